// Round 3
// baseline (25814.301 us; speedup 1.0000x reference)
//
#include <hip/hip_runtime.h>
#include <hip/hip_bf16.h>
#include <cstdint>

// Problem constants
#define B_   64
#define T_   512
#define IN_  512
#define H_   1024
#define O_   512
#define NG   4096              // 4*H, gate-interleaved: n = 4*h + g  (g: 0=i,1=f,2=o,3=c)
#define KC   1536              // IN_ + H_ combined GEMM depth
#define BT   32768             // B*T
#define BH   65536             // B*H
#define NWG  256               // persistent workgroups (1 per CU)

using bs8 = __attribute__((ext_vector_type(8))) short;   // 8 x bf16 (4 VGPRs)
using f4  = __attribute__((ext_vector_type(4))) float;   // 4 x f32

__device__ __forceinline__ ushort f2bf(float f) {
    union { float f; uint32_t u; } v; v.f = f;
    uint32_t r = v.u + 0x7fffu + ((v.u >> 16) & 1u);   // round-to-nearest-even
    return (ushort)(r >> 16);
}
__device__ __forceinline__ float bf2f(ushort u) {
    union { uint32_t u; float f; } v; v.u = ((uint32_t)u) << 16;
    return v.f;
}
__device__ __forceinline__ float sigm(float x) { return 1.f / (1.f + __expf(-x)); }
__device__ __forceinline__ float tanh_(float x) {
    x = fminf(fmaxf(x, -15.f), 15.f);
    float e = __expf(2.f * x);
    return (e - 1.f) / (e + 1.f);
}

// ---------------- conversion / layout kernels ----------------

__global__ void k_cvt_x(const float* __restrict__ x, ushort* __restrict__ xbf) {
    const int n4 = BT * IN_ / 4;
    for (int i = blockIdx.x * blockDim.x + threadIdx.x; i < n4; i += gridDim.x * blockDim.x) {
        f4 v = *reinterpret_cast<const f4*>(x + (size_t)i * 4);
        uint32_t lo = (uint32_t)f2bf(v[0]) | ((uint32_t)f2bf(v[1]) << 16);
        uint32_t hi = (uint32_t)f2bf(v[2]) | ((uint32_t)f2bf(v[3]) << 16);
        uint2 p; p.x = lo; p.y = hi;
        *reinterpret_cast<uint2*>(xbf + (size_t)i * 4) = p;
    }
}

// WcT[n][k] (bf16), n = 4h+g; k<512 -> Wx_g[k][h], k>=512 -> Wh_g[k-512][h]
__global__ void k_build_wcT(const float* __restrict__ xi, const float* __restrict__ xf,
                            const float* __restrict__ xo, const float* __restrict__ xc,
                            const float* __restrict__ hi, const float* __restrict__ hf,
                            const float* __restrict__ ho, const float* __restrict__ hc,
                            ushort* __restrict__ dst) {
    const int total = NG * KC;
    for (int i = blockIdx.x * blockDim.x + threadIdx.x; i < total; i += gridDim.x * blockDim.x) {
        int n = i / KC, k = i - n * KC;
        int g = n & 3, h = n >> 2;
        float v;
        if (k < IN_) {
            const float* s = (g == 0) ? xi : ((g == 1) ? xf : ((g == 2) ? xo : xc));
            v = s[(size_t)k * H_ + h];
        } else {
            const float* s = (g == 0) ? hi : ((g == 1) ? hf : ((g == 2) ? ho : hc));
            v = s[(size_t)(k - IN_) * H_ + h];
        }
        dst[i] = f2bf(v);
    }
}

// WhyT[o][k] = W_hy[k][o]
__global__ void k_build_whyT(const float* __restrict__ w, ushort* __restrict__ dst) {
    const int total = O_ * H_;
    for (int i = blockIdx.x * blockDim.x + threadIdx.x; i < total; i += gridDim.x * blockDim.x) {
        int o = i >> 10, k = i & (H_ - 1);
        dst[i] = f2bf(w[(size_t)k * O_ + o]);
    }
}

__global__ void k_build_bias(const float* __restrict__ bi, const float* __restrict__ bff,
                             const float* __restrict__ bo, const float* __restrict__ bc,
                             float* __restrict__ dst) {
    int i = blockIdx.x * blockDim.x + threadIdx.x;
    if (i < NG) {
        int g = i & 3, h = i >> 2;
        dst[i] = (g == 0) ? bi[h] : ((g == 1) ? bff[h] : ((g == 2) ? bo[h] : bc[h]));
    }
}

// ---------------- persistent LSTM: all T steps in one cooperative launch ----------------
// WG g owns gate rows n0=g*16 (4 h-units), W slice resident in LDS (XOR-swizzled).
// Per step: gates[16][64] = W_lds · [x_t | h_{s}] (K=1536, 4-wave K-split + LDS reduce),
// elementwise (c in registers), h written to hs[s+1], then device-wide flag barrier.
#define WROWB 3072                     // bytes per LDS W row (1536 bf16)
#define WSWZ(row, kbyte) ((row) * WROWB + ((kbyte) ^ (((row) & 7) << 4)))

__global__ void __launch_bounds__(256, 1)
k_persist(const ushort* __restrict__ WcT, const ushort* __restrict__ xbf,
          ushort* __restrict__ hs, float* __restrict__ cst,
          const float* __restrict__ biasc, uint32_t* __restrict__ flags,
          int t0, int nsteps) {
    __shared__ ushort Wl[16 * 1536];           // 48 KB, swizzled
    __shared__ f4 part[4][4][64];              // 16 KB
    const int g = blockIdx.x;
    const int tid = threadIdx.x;
    const int lane = tid & 63, w = tid >> 6;
    const int n0 = g * 16;
    const int l15 = lane & 15, lk = (lane >> 4) * 8;

    // stage W slice into LDS (one-time): 16 rows x 192 chunks of 16B
    {
        char* wb = (char*)Wl;
        for (int i = tid; i < 16 * 192; i += 256) {
            const int row = i / 192, c8 = i - row * 192;
            bs8 v = *reinterpret_cast<const bs8*>(WcT + (size_t)(n0 + row) * KC + c8 * 8);
            *reinterpret_cast<bs8*>(wb + WSWZ(row, c8 * 16)) = v;
        }
    }
    // this thread's (b,h) for the elementwise phase
    const int b_ = w * 16 + l15;
    const int hh = g * 4 + (lane >> 4);
    const f4 bia = *reinterpret_cast<const f4*>(biasc + n0 + (lane >> 4) * 4);
    float creg = (t0 == 0) ? 0.f : cst[(size_t)b_ * H_ + hh];
    // hoisted pointer bases
    const char* wb = (const char*)Wl;
    const ushort* bx[4]; const ushort* bh[4];
#pragma unroll
    for (int n = 0; n < 4; ++n) {
        bx[n] = xbf + ((size_t)(n * 16 + l15) * T_ + t0) * IN_ + lk;
        bh[n] = hs + (size_t)(n * 16 + l15) * H_ + lk;
    }
    __syncthreads();

    for (int s = 0; s < nsteps; ++s) {
        f4 acc[4] = {};
        // x part: wave w covers kk = 4w..4w+3  (k = kk*32+lk)
#pragma unroll
        for (int q = 0; q < 4; ++q) {
            const int kk = w * 4 + q;
            bs8 a = *reinterpret_cast<const bs8*>(wb + WSWZ(l15, (kk * 32 + lk) * 2));
            bs8 b[4];
#pragma unroll
            for (int n = 0; n < 4; ++n)
                b[n] = *reinterpret_cast<const bs8*>(bx[n] + (size_t)s * IN_ + kk * 32);
#pragma unroll
            for (int n = 0; n < 4; ++n)
                acc[n] = __builtin_amdgcn_mfma_f32_16x16x32_bf16(a, b[n], acc[n], 0, 0, 0);
        }
        // h part: wave w covers kk = 8w..8w+7  (k = 512 + kk*32+lk)
#pragma unroll
        for (int q = 0; q < 8; ++q) {
            const int kk = w * 8 + q;
            bs8 a = *reinterpret_cast<const bs8*>(wb + WSWZ(l15, (IN_ + kk * 32 + lk) * 2));
            bs8 b[4];
#pragma unroll
            for (int n = 0; n < 4; ++n)
                b[n] = *reinterpret_cast<const bs8*>(bh[n] + (size_t)s * BH + kk * 32);
#pragma unroll
            for (int n = 0; n < 4; ++n)
                acc[n] = __builtin_amdgcn_mfma_f32_16x16x32_bf16(a, b[n], acc[n], 0, 0, 0);
        }

#pragma unroll
        for (int n = 0; n < 4; ++n) part[w][n][lane] = acc[n];
        __syncthreads();

        // reduce 4 K-partials; elementwise for (b_, hh); write h_{s+1}
        f4 ssum = part[0][w][lane] + part[1][w][lane] + part[2][w][lane] + part[3][w][lane];
        float pi = ssum[0] + bia[0];
        float pf = ssum[1] + bia[1];
        float po = ssum[2] + bia[2];
        float pc = ssum[3] + bia[3];
        float iv = sigm(pi), fv = sigm(pf), ov = sigm(po), cv = tanh_(pc);
        creg = fv * creg + iv * cv;
        float hn = ov * tanh_(creg);
        hs[(size_t)(s + 1) * BH + (size_t)b_ * H_ + hh] = f2bf(hn);

        // device-wide barrier: release own flag, wave 0 polls all 256 flags
        __threadfence();
        __syncthreads();                    // all stores in this WG fenced
        if (tid == 0)
            __hip_atomic_store(&flags[g], (uint32_t)(s + 1),
                               __ATOMIC_RELEASE, __HIP_MEMORY_SCOPE_AGENT);
        if (w == 0) {
            const uint32_t tgt = (uint32_t)(s + 1);
            uint32_t* fp = flags + lane * 4;
            for (;;) {
                uint32_t a0 = __hip_atomic_load(fp + 0, __ATOMIC_RELAXED, __HIP_MEMORY_SCOPE_AGENT);
                uint32_t a1 = __hip_atomic_load(fp + 1, __ATOMIC_RELAXED, __HIP_MEMORY_SCOPE_AGENT);
                uint32_t a2 = __hip_atomic_load(fp + 2, __ATOMIC_RELAXED, __HIP_MEMORY_SCOPE_AGENT);
                uint32_t a3 = __hip_atomic_load(fp + 3, __ATOMIC_RELAXED, __HIP_MEMORY_SCOPE_AGENT);
                if (__all((int)(a0 >= tgt && a1 >= tgt && a2 >= tgt && a3 >= tgt))) break;
                __builtin_amdgcn_s_sleep(4);
            }
        }
        __syncthreads();
        __threadfence();                    // acquire: see other XCDs' h writes
    }
    cst[(size_t)b_ * H_ + hh] = creg;       // persist c for chunked (tier B) mode
}

// ---------------- fallback per-step kernel (round-2 structure) ----------------
__global__ void __launch_bounds__(256) k_step(const ushort* __restrict__ WcT,
                                              const ushort* __restrict__ xbf, int t,
                                              const ushort* __restrict__ hprev,
                                              ushort* __restrict__ hnext,
                                              const float* __restrict__ biasc,
                                              float* __restrict__ cst) {
    __shared__ f4 part[4][4][64];
    const int lane = threadIdx.x & 63;
    const int w = threadIdx.x >> 6;
    const int n0 = blockIdx.x * 16;
    const int l15 = lane & 15, lk = (lane >> 4) * 8;

    f4 acc[4] = {};
    const ushort* ap = WcT + (size_t)(n0 + l15) * KC + lk;
    {
        const ushort* bp[4];
#pragma unroll
        for (int n = 0; n < 4; ++n)
            bp[n] = xbf + ((size_t)(n * 16 + l15) * T_ + t) * IN_ + lk;
#pragma unroll
        for (int q = 0; q < 4; ++q) {
            const int kk = w * 4 + q;
            bs8 a = *reinterpret_cast<const bs8*>(ap + kk * 32);
            bs8 b[4];
#pragma unroll
            for (int n = 0; n < 4; ++n) b[n] = *reinterpret_cast<const bs8*>(bp[n] + kk * 32);
#pragma unroll
            for (int n = 0; n < 4; ++n)
                acc[n] = __builtin_amdgcn_mfma_f32_16x16x32_bf16(a, b[n], acc[n], 0, 0, 0);
        }
    }
    {
        const ushort* ah = ap + IN_;
        const ushort* bp[4];
#pragma unroll
        for (int n = 0; n < 4; ++n)
            bp[n] = hprev + (size_t)(n * 16 + l15) * H_ + lk;
#pragma unroll
        for (int q = 0; q < 8; ++q) {
            const int kk = w * 8 + q;
            bs8 a = *reinterpret_cast<const bs8*>(ah + kk * 32);
            bs8 b[4];
#pragma unroll
            for (int n = 0; n < 4; ++n) b[n] = *reinterpret_cast<const bs8*>(bp[n] + kk * 32);
#pragma unroll
            for (int n = 0; n < 4; ++n)
                acc[n] = __builtin_amdgcn_mfma_f32_16x16x32_bf16(a, b[n], acc[n], 0, 0, 0);
        }
    }
#pragma unroll
    for (int n = 0; n < 4; ++n) part[w][n][lane] = acc[n];
    __syncthreads();
    f4 s = part[0][w][lane] + part[1][w][lane] + part[2][w][lane] + part[3][w][lane];
    const int nb = n0 + (lane >> 4) * 4;
    const int h = nb >> 2;
    const int b_ = w * 16 + l15;
    const f4 bia = *reinterpret_cast<const f4*>(biasc + nb);
    float pi = s[0] + bia[0];
    float pf = s[1] + bia[1];
    float po = s[2] + bia[2];
    float pc = s[3] + bia[3];
    float iv = sigm(pi), fv = sigm(pf), ov = sigm(po), cv = tanh_(pc);
    float co = cst[(size_t)b_ * H_ + h];
    float cn = fv * co + iv * cv;
    float hn = ov * tanh_(cn);
    cst[(size_t)b_ * H_ + h] = cn;
    hnext[(size_t)b_ * H_ + h] = f2bf(hn);
}

// ---------------- output projection ----------------
__global__ void __launch_bounds__(64) k_yproj(const ushort* __restrict__ WhyT,
                                              const ushort* __restrict__ hsn,
                                              const float* __restrict__ by,
                                              float* __restrict__ out, int t_off) {
    const int lane = threadIdx.x;
    const int r0 = blockIdx.x * 64;
    const int o0 = blockIdx.y * 64;
    const int l15 = lane & 15, lk = (lane >> 4) * 8;

    const ushort* apm[4]; const ushort* bp[4];
#pragma unroll
    for (int m = 0; m < 4; ++m) apm[m] = WhyT + (size_t)(o0 + m * 16 + l15) * H_ + lk;
#pragma unroll
    for (int n = 0; n < 4; ++n) bp[n] = hsn + (size_t)(r0 + n * 16 + l15) * H_ + lk;

    f4 acc[4][4] = {};
    for (int kk = 0; kk < H_ / 32; ++kk) {
        bs8 a[4], b[4];
#pragma unroll
        for (int m = 0; m < 4; ++m) a[m] = *reinterpret_cast<const bs8*>(apm[m] + kk * 32);
#pragma unroll
        for (int n = 0; n < 4; ++n) b[n] = *reinterpret_cast<const bs8*>(bp[n] + kk * 32);
#pragma unroll
        for (int m = 0; m < 4; ++m)
#pragma unroll
            for (int n = 0; n < 4; ++n)
                acc[m][n] = __builtin_amdgcn_mfma_f32_16x16x32_bf16(a[m], b[n], acc[m][n], 0, 0, 0);
    }

#pragma unroll
    for (int m = 0; m < 4; ++m) {
        const int ob = o0 + m * 16 + (lane >> 4) * 4;
        const f4 bb = *reinterpret_cast<const f4*>(by + ob);
#pragma unroll
        for (int n = 0; n < 4; ++n) {
            const int r = r0 + n * 16 + l15;
            const int t = t_off + (r >> 6), b_ = r & 63;
            f4 v = acc[m][n] + bb;
            *reinterpret_cast<f4*>(out + ((size_t)b_ * T_ + t) * O_ + ob) = v;
        }
    }
}

// ---------------- launch ----------------

extern "C" void kernel_launch(void* const* d_in, const int* in_sizes, int n_in,
                              void* d_out, int out_size, void* d_ws, size_t ws_size,
                              hipStream_t stream) {
    const float* x   = (const float*)d_in[0];
    const float* wxi = (const float*)d_in[1];
    const float* whi = (const float*)d_in[2];
    const float* bi  = (const float*)d_in[3];
    const float* wxf = (const float*)d_in[4];
    const float* whf = (const float*)d_in[5];
    const float* bf_ = (const float*)d_in[6];
    const float* wxo = (const float*)d_in[7];
    const float* who = (const float*)d_in[8];
    const float* bo  = (const float*)d_in[9];
    const float* wxc = (const float*)d_in[10];
    const float* whc = (const float*)d_in[11];
    const float* bc  = (const float*)d_in[12];
    const float* why = (const float*)d_in[13];
    const float* by  = (const float*)d_in[14];
    float* out = (float*)d_out;

    // workspace layout (bytes)
    uint8_t* w = (uint8_t*)d_ws;
    ushort*   xbf   = (ushort*)  (w);                  // 33,554,432
    ushort*   WcT   = (ushort*)  (w + 33554432);       // 12,582,912
    ushort*   WhyT  = (ushort*)  (w + 46137344);       //  1,048,576
    float*    biasc = (float*)   (w + 47185920);       //     16,384
    float*    cst   = (float*)   (w + 47202304);       //    262,144
    uint32_t* flags = (uint32_t*)(w + 47464448);       //      4,096
    ushort*   hs    = (ushort*)  (w + 47468544);       // tier-dependent
    const size_t NEED_A = 47468544 + (size_t)(T_ + 1) * BH * 2;  // 114,708,480
    const size_t NEED_B = 47468544 + (size_t)65 * BH * 2;        //  55,988,224
    if (ws_size < NEED_B) return;
    const bool fullhs = (ws_size >= NEED_A);

    // 1) conversions / packed-weight builds
    k_cvt_x<<<2048, 256, 0, stream>>>(x, xbf);
    k_build_wcT<<<4096, 256, 0, stream>>>(wxi, wxf, wxo, wxc, whi, whf, who, whc, WcT);
    k_build_whyT<<<512, 256, 0, stream>>>(why, WhyT);
    k_build_bias<<<16, 256, 0, stream>>>(bi, bf_, bo, bc, biasc);

    // 2) state init
    hipMemsetAsync(cst, 0, (size_t)BH * 4, stream);
    hipMemsetAsync(hs,  0, (size_t)BH * 2, stream);

    const int nchunk = fullhs ? 1 : 8;
    const int steps  = fullhs ? T_ : 64;
    for (int c = 0; c < nchunk; ++c) {
        const int t0 = c * steps;
        hipMemsetAsync(flags, 0, NWG * 4, stream);
        const ushort* a0 = WcT; const ushort* a1 = xbf; ushort* a2 = hs;
        float* a3 = cst; const float* a4 = biasc; uint32_t* a5 = flags;
        int a6 = t0, a7 = steps;
        void* args[8] = {&a0, &a1, &a2, &a3, &a4, &a5, &a6, &a7};
        hipError_t e = hipLaunchCooperativeKernel((const void*)k_persist,
                                                  dim3(NWG), dim3(256), args, 0, stream);
        if (e != hipSuccess) {
            // fallback: per-step launches (round-2 path)
            for (int s = 0; s < steps; ++s) {
                const int t = t0 + s;
                k_step<<<NG / 16, 256, 0, stream>>>(WcT, xbf, t, hs + (size_t)s * BH,
                                                    hs + (size_t)(s + 1) * BH, biasc, cst);
            }
        }
        if (!fullhs) {
            k_yproj<<<dim3(64, O_ / 64), 64, 0, stream>>>(WhyT, hs + BH, by, out, t0);
            if (c != nchunk - 1)
                hipMemcpyAsync(hs, hs + (size_t)64 * BH, (size_t)BH * 2,
                               hipMemcpyDeviceToDevice, stream);
        }
    }
    if (fullhs)
        k_yproj<<<dim3(BT / 64, O_ / 64), 64, 0, stream>>>(WhyT, hs + BH, by, out, 0);
}

// Round 4
// 6448.105 us; speedup vs baseline: 4.0034x; 4.0034x over previous
//
#include <hip/hip_runtime.h>
#include <hip/hip_bf16.h>
#include <cstdint>

// Problem constants
#define B_   64
#define T_   512
#define IN_  512
#define H_   1024
#define O_   512
#define NG   4096              // 4*H, gate-interleaved: n = 4*h + g  (g: 0=i,1=f,2=o,3=c)
#define KC   1536              // IN_ + H_ combined GEMM depth
#define BT   32768             // B*T
#define BH   65536             // B*H
#define NWG  128               // persistent workgroups (rows = NG/NWG = 32 per WG)

using bs8 = __attribute__((ext_vector_type(8))) short;   // 8 x bf16 (4 VGPRs)
using f4  = __attribute__((ext_vector_type(4))) float;   // 4 x f32

__device__ __forceinline__ ushort f2bf(float f) {
    union { float f; uint32_t u; } v; v.f = f;
    uint32_t r = v.u + 0x7fffu + ((v.u >> 16) & 1u);   // round-to-nearest-even
    return (ushort)(r >> 16);
}
__device__ __forceinline__ float bf2f(ushort u) {
    union { uint32_t u; float f; } v; v.u = ((uint32_t)u) << 16;
    return v.f;
}
__device__ __forceinline__ float sigm(float x) { return 1.f / (1.f + __expf(-x)); }
__device__ __forceinline__ float tanh_(float x) {
    x = fminf(fmaxf(x, -15.f), 15.f);
    float e = __expf(2.f * x);
    return (e - 1.f) / (e + 1.f);
}

// coherent 16B store: write-through to device coherence point (L3), no cache nukes
__device__ __forceinline__ void coh_store16(void* p, f4 v) {
    asm volatile("global_store_dwordx4 %0, %1, off sc0 sc1" :: "v"(p), "v"(v) : "memory");
}

// ---------------- conversion / layout kernels ----------------

__global__ void k_cvt_x(const float* __restrict__ x, ushort* __restrict__ xbf) {
    const int n4 = BT * IN_ / 4;
    for (int i = blockIdx.x * blockDim.x + threadIdx.x; i < n4; i += gridDim.x * blockDim.x) {
        f4 v = *reinterpret_cast<const f4*>(x + (size_t)i * 4);
        uint32_t lo = (uint32_t)f2bf(v[0]) | ((uint32_t)f2bf(v[1]) << 16);
        uint32_t hi = (uint32_t)f2bf(v[2]) | ((uint32_t)f2bf(v[3]) << 16);
        uint2 p; p.x = lo; p.y = hi;
        *reinterpret_cast<uint2*>(xbf + (size_t)i * 4) = p;
    }
}

// WcT[n][k] (bf16), n = 4h+g; k<512 -> Wx_g[k][h], k>=512 -> Wh_g[k-512][h]
__global__ void k_build_wcT(const float* __restrict__ xi, const float* __restrict__ xf,
                            const float* __restrict__ xo, const float* __restrict__ xc,
                            const float* __restrict__ hi, const float* __restrict__ hf,
                            const float* __restrict__ ho, const float* __restrict__ hc,
                            ushort* __restrict__ dst) {
    const int total = NG * KC;
    for (int i = blockIdx.x * blockDim.x + threadIdx.x; i < total; i += gridDim.x * blockDim.x) {
        int n = i / KC, k = i - n * KC;
        int g = n & 3, h = n >> 2;
        float v;
        if (k < IN_) {
            const float* s = (g == 0) ? xi : ((g == 1) ? xf : ((g == 2) ? xo : xc));
            v = s[(size_t)k * H_ + h];
        } else {
            const float* s = (g == 0) ? hi : ((g == 1) ? hf : ((g == 2) ? ho : hc));
            v = s[(size_t)(k - IN_) * H_ + h];
        }
        dst[i] = f2bf(v);
    }
}

// WhyT[o][k] = W_hy[k][o]
__global__ void k_build_whyT(const float* __restrict__ w, ushort* __restrict__ dst) {
    const int total = O_ * H_;
    for (int i = blockIdx.x * blockDim.x + threadIdx.x; i < total; i += gridDim.x * blockDim.x) {
        int o = i >> 10, k = i & (H_ - 1);
        dst[i] = f2bf(w[(size_t)k * O_ + o]);
    }
}

__global__ void k_build_bias(const float* __restrict__ bi, const float* __restrict__ bff,
                             const float* __restrict__ bo, const float* __restrict__ bc,
                             float* __restrict__ dst) {
    int i = blockIdx.x * blockDim.x + threadIdx.x;
    if (i < NG) {
        int g = i & 3, h = i >> 2;
        dst[i] = (g == 0) ? bi[h] : ((g == 1) ? bff[h] : ((g == 2) ? bo[h] : bc[h]));
    }
}

// ---------------- persistent LSTM ----------------
// WG g owns gate rows n0=g*32 (8 h-units), W slice (32x1536 bf16 = 96 KB) in swizzled LDS.
// 2 waves; wave w owns b-half w (32 b = 2 MFMA b-tiles), full K.
// Coherence: h stores sc0/sc1 write-through; flags relaxed agent atomics; NO threadfence.
// Barrier latency hidden under next step's x-part MFMA.
#define WROWB 3072                     // bytes per LDS W row (1536 bf16)
#define WSWZ(row, kbyte) ((row) * WROWB + ((kbyte) ^ (((row) & 7) << 4)))

__global__ void __launch_bounds__(128, 1)
k_persist(const ushort* __restrict__ WcT, const ushort* __restrict__ xbf,
          ushort* __restrict__ hs, float* __restrict__ cst,
          const float* __restrict__ biasc, uint32_t* __restrict__ flags,
          int t0, int nsteps) {
    __shared__ ushort Wl[32 * 1536];           // 96 KB, swizzled
    __shared__ ushort hout[64][8];             // 1 KB repack buffer
    const int g = blockIdx.x;
    const int tid = threadIdx.x;
    const int lane = tid & 63, w = tid >> 6;   // w = b-half
    const int n0 = g * 32;
    const int l15 = lane & 15, lq = lane >> 4, lk = lq * 8;

    // stage W slice into LDS (one-time): 32 rows x 192 chunks of 16B
    {
        char* wbp = (char*)Wl;
        for (int i = tid; i < 32 * 192; i += 128) {
            const int row = i / 192, c8 = i - row * 192;
            bs8 v = *reinterpret_cast<const bs8*>(WcT + (size_t)(n0 + row) * KC + c8 * 8);
            *reinterpret_cast<bs8*>(wbp + WSWZ(row, c8 * 16)) = v;
        }
    }
    const char* wbp = (const char*)Wl;

    // per-thread cells: (m, bt): b = w*32 + bt*16 + l15, h-unit = g*8 + m*4 + lq
    const int bcell[2] = { w * 32 + 0 * 16 + l15, w * 32 + 1 * 16 + l15 };
    const int hcell[2] = { g * 8 + 0 * 4 + lq,   g * 8 + 1 * 4 + lq };
    f4 bia[2];
    bia[0] = *reinterpret_cast<const f4*>(biasc + n0 + 0 * 16 + lq * 4);
    bia[1] = *reinterpret_cast<const f4*>(biasc + n0 + 1 * 16 + lq * 4);
    float creg[2][2];
#pragma unroll
    for (int m = 0; m < 2; ++m)
#pragma unroll
        for (int bt = 0; bt < 2; ++bt)
            creg[m][bt] = (t0 == 0) ? 0.f : cst[(size_t)bcell[bt] * H_ + hcell[m]];

    // load bases (b-operand): col = l15 -> row b, k = kk*32 + lk + j
    const ushort* xb[2]; const ushort* hb[2];
#pragma unroll
    for (int bt = 0; bt < 2; ++bt) {
        xb[bt] = xbf + ((size_t)bcell[bt] * T_ + t0) * IN_ + lk;
        hb[bt] = hs + (size_t)bcell[bt] * H_ + lk;
    }
    __syncthreads();

    f4 acc[2][2];

    // x-part for step s (K = 0..511): 16 kk, 2 A-rows, 2 b-tiles
    auto xpart = [&](int s) {
#pragma unroll
        for (int m = 0; m < 2; ++m)
#pragma unroll
            for (int bt = 0; bt < 2; ++bt) acc[m][bt] = (f4){0.f, 0.f, 0.f, 0.f};
#pragma unroll
        for (int kk = 0; kk < 16; ++kk) {
            bs8 a0 = *reinterpret_cast<const bs8*>(wbp + WSWZ(l15,      kk * 64 + lq * 16));
            bs8 a1 = *reinterpret_cast<const bs8*>(wbp + WSWZ(16 + l15, kk * 64 + lq * 16));
            bs8 b0 = *reinterpret_cast<const bs8*>(xb[0] + (size_t)s * IN_ + kk * 32);
            bs8 b1 = *reinterpret_cast<const bs8*>(xb[1] + (size_t)s * IN_ + kk * 32);
            acc[0][0] = __builtin_amdgcn_mfma_f32_16x16x32_bf16(a0, b0, acc[0][0], 0, 0, 0);
            acc[0][1] = __builtin_amdgcn_mfma_f32_16x16x32_bf16(a0, b1, acc[0][1], 0, 0, 0);
            acc[1][0] = __builtin_amdgcn_mfma_f32_16x16x32_bf16(a1, b0, acc[1][0], 0, 0, 0);
            acc[1][1] = __builtin_amdgcn_mfma_f32_16x16x32_bf16(a1, b1, acc[1][1], 0, 0, 0);
        }
    };

    xpart(0);

    for (int s = 0; s < nsteps; ++s) {
        // h-part (K = 512..1535): 32 kk; h_s guaranteed visible by previous poll
        const ushort* h0 = hb[0] + (size_t)s * BH;
        const ushort* h1 = hb[1] + (size_t)s * BH;
#pragma unroll
        for (int kk = 0; kk < 32; ++kk) {
            bs8 a0 = *reinterpret_cast<const bs8*>(wbp + WSWZ(l15,      1024 + kk * 64 + lq * 16));
            bs8 a1 = *reinterpret_cast<const bs8*>(wbp + WSWZ(16 + l15, 1024 + kk * 64 + lq * 16));
            bs8 b0 = *reinterpret_cast<const bs8*>(h0 + kk * 32);
            bs8 b1 = *reinterpret_cast<const bs8*>(h1 + kk * 32);
            acc[0][0] = __builtin_amdgcn_mfma_f32_16x16x32_bf16(a0, b0, acc[0][0], 0, 0, 0);
            acc[0][1] = __builtin_amdgcn_mfma_f32_16x16x32_bf16(a0, b1, acc[0][1], 0, 0, 0);
            acc[1][0] = __builtin_amdgcn_mfma_f32_16x16x32_bf16(a1, b0, acc[1][0], 0, 0, 0);
            acc[1][1] = __builtin_amdgcn_mfma_f32_16x16x32_bf16(a1, b1, acc[1][1], 0, 0, 0);
        }

        // elementwise: 4 cells per thread; write bf16 h to LDS repack buffer
#pragma unroll
        for (int m = 0; m < 2; ++m)
#pragma unroll
            for (int bt = 0; bt < 2; ++bt) {
                float pi = acc[m][bt][0] + bia[m][0];
                float pf = acc[m][bt][1] + bia[m][1];
                float po = acc[m][bt][2] + bia[m][2];
                float pc = acc[m][bt][3] + bia[m][3];
                float iv = sigm(pi), fv = sigm(pf), ov = sigm(po), cv = tanh_(pc);
                creg[m][bt] = fv * creg[m][bt] + iv * cv;
                float hn = ov * tanh_(creg[m][bt]);
                hout[w * 32 + bt * 16 + l15][m * 4 + lq] = f2bf(hn);
            }
        __syncthreads();

        // wave 0: repack -> coherent 16B store of h_{s+1}; release flag
        if (w == 0) {
            f4 hv = *reinterpret_cast<f4*>(&hout[lane][0]);
            coh_store16(hs + (size_t)(s + 1) * BH + (size_t)lane * H_ + g * 8, hv);
            asm volatile("s_waitcnt vmcnt(0)" ::: "memory");
            if (tid == 0)
                __hip_atomic_store(&flags[g], (uint32_t)(s + 1),
                                   __ATOMIC_RELAXED, __HIP_MEMORY_SCOPE_AGENT);
        }

        if (s + 1 < nsteps) {
            // hide barrier latency: compute next step's x-part (independent of h)
            xpart(s + 1);
            // wave 0 polls all NWG flags (2 per lane)
            if (w == 0) {
                const uint32_t tgt = (uint32_t)(s + 1);
                for (;;) {
                    uint32_t f0 = __hip_atomic_load(&flags[lane], __ATOMIC_RELAXED,
                                                    __HIP_MEMORY_SCOPE_AGENT);
                    uint32_t f1 = __hip_atomic_load(&flags[64 + lane], __ATOMIC_RELAXED,
                                                    __HIP_MEMORY_SCOPE_AGENT);
                    if (__all((int)(f0 >= tgt && f1 >= tgt))) break;
                    __builtin_amdgcn_s_sleep(2);
                }
            }
            __syncthreads();   // full compiler+HW barrier: h-part loads can't start early
        }
    }

    // persist c (needed for chunked tier-B mode)
#pragma unroll
    for (int m = 0; m < 2; ++m)
#pragma unroll
        for (int bt = 0; bt < 2; ++bt)
            cst[(size_t)bcell[bt] * H_ + hcell[m]] = creg[m][bt];
}

// ---------------- fallback per-step kernel (round-2 structure, proven) ----------------
__global__ void __launch_bounds__(256) k_step(const ushort* __restrict__ WcT,
                                              const ushort* __restrict__ xbf, int t,
                                              const ushort* __restrict__ hprev,
                                              ushort* __restrict__ hnext,
                                              const float* __restrict__ biasc,
                                              float* __restrict__ cst) {
    __shared__ f4 part[4][4][64];
    const int lane = threadIdx.x & 63;
    const int w = threadIdx.x >> 6;
    const int n0 = blockIdx.x * 16;
    const int l15 = lane & 15, lk = (lane >> 4) * 8;

    f4 acc[4] = {};
    const ushort* ap = WcT + (size_t)(n0 + l15) * KC + lk;
    {
        const ushort* bp[4];
#pragma unroll
        for (int n = 0; n < 4; ++n)
            bp[n] = xbf + ((size_t)(n * 16 + l15) * T_ + t) * IN_ + lk;
#pragma unroll
        for (int q = 0; q < 4; ++q) {
            const int kk = w * 4 + q;
            bs8 a = *reinterpret_cast<const bs8*>(ap + kk * 32);
            bs8 b[4];
#pragma unroll
            for (int n = 0; n < 4; ++n) b[n] = *reinterpret_cast<const bs8*>(bp[n] + kk * 32);
#pragma unroll
            for (int n = 0; n < 4; ++n)
                acc[n] = __builtin_amdgcn_mfma_f32_16x16x32_bf16(a, b[n], acc[n], 0, 0, 0);
        }
    }
    {
        const ushort* ah = ap + IN_;
        const ushort* bp[4];
#pragma unroll
        for (int n = 0; n < 4; ++n)
            bp[n] = hprev + (size_t)(n * 16 + l15) * H_ + lk;
#pragma unroll
        for (int q = 0; q < 8; ++q) {
            const int kk = w * 8 + q;
            bs8 a = *reinterpret_cast<const bs8*>(ah + kk * 32);
            bs8 b[4];
#pragma unroll
            for (int n = 0; n < 4; ++n) b[n] = *reinterpret_cast<const bs8*>(bp[n] + kk * 32);
#pragma unroll
            for (int n = 0; n < 4; ++n)
                acc[n] = __builtin_amdgcn_mfma_f32_16x16x32_bf16(a, b[n], acc[n], 0, 0, 0);
        }
    }
#pragma unroll
    for (int n = 0; n < 4; ++n) part[w][n][lane] = acc[n];
    __syncthreads();
    f4 s = part[0][w][lane] + part[1][w][lane] + part[2][w][lane] + part[3][w][lane];
    const int nb = n0 + (lane >> 4) * 4;
    const int h = nb >> 2;
    const int b_ = w * 16 + l15;
    const f4 bia = *reinterpret_cast<const f4*>(biasc + nb);
    float pi = s[0] + bia[0];
    float pf = s[1] + bia[1];
    float po = s[2] + bia[2];
    float pc = s[3] + bia[3];
    float iv = sigm(pi), fv = sigm(pf), ov = sigm(po), cv = tanh_(pc);
    float co = cst[(size_t)b_ * H_ + h];
    float cn = fv * co + iv * cv;
    float hn = ov * tanh_(cn);
    cst[(size_t)b_ * H_ + h] = cn;
    hnext[(size_t)b_ * H_ + h] = f2bf(hn);
}

// ---------------- output projection ----------------
__global__ void __launch_bounds__(64) k_yproj(const ushort* __restrict__ WhyT,
                                              const ushort* __restrict__ hsn,
                                              const float* __restrict__ by,
                                              float* __restrict__ out, int t_off) {
    const int lane = threadIdx.x;
    const int r0 = blockIdx.x * 64;
    const int o0 = blockIdx.y * 64;
    const int l15 = lane & 15, lk = (lane >> 4) * 8;

    const ushort* apm[4]; const ushort* bp[4];
#pragma unroll
    for (int m = 0; m < 4; ++m) apm[m] = WhyT + (size_t)(o0 + m * 16 + l15) * H_ + lk;
#pragma unroll
    for (int n = 0; n < 4; ++n) bp[n] = hsn + (size_t)(r0 + n * 16 + l15) * H_ + lk;

    f4 acc[4][4] = {};
    for (int kk = 0; kk < H_ / 32; ++kk) {
        bs8 a[4], b[4];
#pragma unroll
        for (int m = 0; m < 4; ++m) a[m] = *reinterpret_cast<const bs8*>(apm[m] + kk * 32);
#pragma unroll
        for (int n = 0; n < 4; ++n) b[n] = *reinterpret_cast<const bs8*>(bp[n] + kk * 32);
#pragma unroll
        for (int m = 0; m < 4; ++m)
#pragma unroll
            for (int n = 0; n < 4; ++n)
                acc[m][n] = __builtin_amdgcn_mfma_f32_16x16x32_bf16(a[m], b[n], acc[m][n], 0, 0, 0);
    }

#pragma unroll
    for (int m = 0; m < 4; ++m) {
        const int ob = o0 + m * 16 + (lane >> 4) * 4;
        const f4 bb = *reinterpret_cast<const f4*>(by + ob);
#pragma unroll
        for (int n = 0; n < 4; ++n) {
            const int r = r0 + n * 16 + l15;
            const int t = t_off + (r >> 6), b_ = r & 63;
            f4 v = acc[m][n] + bb;
            *reinterpret_cast<f4*>(out + ((size_t)b_ * T_ + t) * O_ + ob) = v;
        }
    }
}

// ---------------- launch ----------------

extern "C" void kernel_launch(void* const* d_in, const int* in_sizes, int n_in,
                              void* d_out, int out_size, void* d_ws, size_t ws_size,
                              hipStream_t stream) {
    const float* x   = (const float*)d_in[0];
    const float* wxi = (const float*)d_in[1];
    const float* whi = (const float*)d_in[2];
    const float* bi  = (const float*)d_in[3];
    const float* wxf = (const float*)d_in[4];
    const float* whf = (const float*)d_in[5];
    const float* bf_ = (const float*)d_in[6];
    const float* wxo = (const float*)d_in[7];
    const float* who = (const float*)d_in[8];
    const float* bo  = (const float*)d_in[9];
    const float* wxc = (const float*)d_in[10];
    const float* whc = (const float*)d_in[11];
    const float* bc  = (const float*)d_in[12];
    const float* why = (const float*)d_in[13];
    const float* by  = (const float*)d_in[14];
    float* out = (float*)d_out;

    // workspace layout (bytes)
    uint8_t* w = (uint8_t*)d_ws;
    ushort*   xbf   = (ushort*)  (w);                  // 33,554,432
    ushort*   WcT   = (ushort*)  (w + 33554432);       // 12,582,912
    ushort*   WhyT  = (ushort*)  (w + 46137344);       //  1,048,576
    float*    biasc = (float*)   (w + 47185920);       //     16,384
    float*    cst   = (float*)   (w + 47202304);       //    262,144
    uint32_t* flags = (uint32_t*)(w + 47464448);       //      4,096
    ushort*   hs    = (ushort*)  (w + 47468544);       // tier-dependent
    const size_t NEED_A = 47468544 + (size_t)(T_ + 1) * BH * 2;  // 114,708,480
    const size_t NEED_B = 47468544 + (size_t)65 * BH * 2;        //  55,988,224
    if (ws_size < NEED_B) return;
    const bool fullhs = (ws_size >= NEED_A);

    // 1) conversions / packed-weight builds
    k_cvt_x<<<2048, 256, 0, stream>>>(x, xbf);
    k_build_wcT<<<4096, 256, 0, stream>>>(wxi, wxf, wxo, wxc, whi, whf, who, whc, WcT);
    k_build_whyT<<<512, 256, 0, stream>>>(why, WhyT);
    k_build_bias<<<16, 256, 0, stream>>>(bi, bf_, bo, bc, biasc);

    // 2) state init
    hipMemsetAsync(cst, 0, (size_t)BH * 4, stream);
    hipMemsetAsync(hs,  0, (size_t)BH * 2, stream);

    const int nchunk = fullhs ? 1 : 8;
    const int steps  = fullhs ? T_ : 64;
    for (int c = 0; c < nchunk; ++c) {
        const int t0 = c * steps;
        hipMemsetAsync(flags, 0, NWG * 4, stream);
        const ushort* a0 = WcT; const ushort* a1 = xbf; ushort* a2 = hs;
        float* a3 = cst; const float* a4 = biasc; uint32_t* a5 = flags;
        int a6 = t0, a7 = steps;
        void* args[8] = {&a0, &a1, &a2, &a3, &a4, &a5, &a6, &a7};
        hipError_t e = hipLaunchCooperativeKernel((const void*)k_persist,
                                                  dim3(NWG), dim3(128), args, 0, stream);
        if (e != hipSuccess) {
            for (int s = 0; s < steps; ++s) {
                const int t = t0 + s;
                k_step<<<NG / 16, 256, 0, stream>>>(WcT, xbf, t, hs + (size_t)s * BH,
                                                    hs + (size_t)(s + 1) * BH, biasc, cst);
            }
        }
        if (!fullhs) {
            k_yproj<<<dim3(64, O_ / 64), 64, 0, stream>>>(WhyT, hs + BH, by, out, t0);
            if (c != nchunk - 1)
                hipMemcpyAsync(hs, hs + (size_t)64 * BH, (size_t)BH * 2,
                               hipMemcpyDeviceToDevice, stream);
        }
    }
    if (fullhs)
        k_yproj<<<dim3(BT / 64, O_ / 64), 64, 0, stream>>>(WhyT, hs + BH, by, out, 0);
}

// Round 5
// 2876.722 us; speedup vs baseline: 8.9735x; 2.2415x over previous
//
#include <hip/hip_runtime.h>
#include <hip/hip_bf16.h>
#include <cstdint>

// Problem constants
#define B_   64
#define T_   512
#define IN_  512
#define H_   1024
#define O_   512
#define NG   4096              // 4*H, gate-interleaved: n = 4h+g
#define KC   1536              // IN_ + H_
#define BT   32768             // B*T
#define BH   65536             // ushorts per h slot (B*H)
#define NWG  128

using bs8 = __attribute__((ext_vector_type(8))) short;   // 8 x bf16
using f4  = __attribute__((ext_vector_type(4))) float;

__device__ __forceinline__ ushort f2bf(float f) {
    union { float f; uint32_t u; } v; v.f = f;
    uint32_t r = v.u + 0x7fffu + ((v.u >> 16) & 1u);
    return (ushort)(r >> 16);
}
__device__ __forceinline__ float sigm(float x) { return 1.f / (1.f + __expf(-x)); }
__device__ __forceinline__ float tanh_(float x) {
    x = fminf(fmaxf(x, -15.f), 15.f);
    float e = __expf(2.f * x);
    return (e - 1.f) / (e + 1.f);
}
__device__ __forceinline__ void coh_store16(void* p, f4 v) {
    asm volatile("global_store_dwordx4 %0, %1, off sc0 sc1" :: "v"(p), "v"(v) : "memory");
}

// ---------------- conversion / layout kernels ----------------

// xP[t][kk][b][32] (kk = k/32, 16 chunks of IN_), fully coalesced consumer reads
__global__ void k_pack_x(const float* __restrict__ x, ushort* __restrict__ xP) {
    const int n8 = BT * IN_ / 8;
    for (int i = blockIdx.x * blockDim.x + threadIdx.x; i < n8; i += gridDim.x * blockDim.x) {
        const int e8 = i & 3, b = (i >> 2) & 63, kk = (i >> 8) & 15, t = i >> 12;
        const float* s = x + ((size_t)b * T_ + t) * IN_ + kk * 32 + e8 * 8;
        f4 v0 = *reinterpret_cast<const f4*>(s);
        f4 v1 = *reinterpret_cast<const f4*>(s + 4);
        uint4 q;
        q.x = (uint32_t)f2bf(v0[0]) | ((uint32_t)f2bf(v0[1]) << 16);
        q.y = (uint32_t)f2bf(v0[2]) | ((uint32_t)f2bf(v0[3]) << 16);
        q.z = (uint32_t)f2bf(v1[0]) | ((uint32_t)f2bf(v1[1]) << 16);
        q.w = (uint32_t)f2bf(v1[2]) | ((uint32_t)f2bf(v1[3]) << 16);
        *reinterpret_cast<uint4*>(xP + ((size_t)t * 16 + kk) * 2048 + b * 32 + e8 * 8) = q;
    }
}

// WcT[n][k] (bf16), n = 4h+g; k<512 -> Wx_g[k][h], k>=512 -> Wh_g[k-512][h]
__global__ void k_build_wcT(const float* __restrict__ xi, const float* __restrict__ xf,
                            const float* __restrict__ xo, const float* __restrict__ xc,
                            const float* __restrict__ hi, const float* __restrict__ hf,
                            const float* __restrict__ ho, const float* __restrict__ hc,
                            ushort* __restrict__ dst) {
    const int total = NG * KC;
    for (int i = blockIdx.x * blockDim.x + threadIdx.x; i < total; i += gridDim.x * blockDim.x) {
        int n = i / KC, k = i - n * KC;
        int g = n & 3, h = n >> 2;
        float v;
        if (k < IN_) {
            const float* s = (g == 0) ? xi : ((g == 1) ? xf : ((g == 2) ? xo : xc));
            v = s[(size_t)k * H_ + h];
        } else {
            const float* s = (g == 0) ? hi : ((g == 1) ? hf : ((g == 2) ? ho : hc));
            v = s[(size_t)(k - IN_) * H_ + h];
        }
        dst[i] = f2bf(v);
    }
}

__global__ void k_build_whyT(const float* __restrict__ w, ushort* __restrict__ dst) {
    const int total = O_ * H_;
    for (int i = blockIdx.x * blockDim.x + threadIdx.x; i < total; i += gridDim.x * blockDim.x) {
        int o = i >> 10, k = i & (H_ - 1);
        dst[i] = f2bf(w[(size_t)k * O_ + o]);
    }
}

__global__ void k_build_bias(const float* __restrict__ bi, const float* __restrict__ bff,
                             const float* __restrict__ bo, const float* __restrict__ bc,
                             float* __restrict__ dst) {
    int i = blockIdx.x * blockDim.x + threadIdx.x;
    if (i < NG) {
        int g = i & 3, h = i >> 2;
        dst[i] = (g == 0) ? bi[h] : ((g == 1) ? bff[h] : ((g == 2) ? bo[h] : bc[h]));
    }
}

// ---------------- persistent LSTM ----------------
// WG g: gate rows n0=g*32 (8 h-units), W in swizzled LDS (96 KB).
// 4 waves; wave w owns b-tile w (16 b), full K. Packed coalesced x/h loads,
// register pipeline: x(s+1) issued pre-poll; h staged 16+16.
#define WROWB 3072
#define WSWZ(row, kbyte) ((row) * WROWB + ((kbyte) ^ (((row) & 7) << 4)))

__global__ void __launch_bounds__(256, 1)
k_persist(const ushort* __restrict__ WcT, const ushort* __restrict__ xP,
          ushort* __restrict__ hs, float* __restrict__ cst,
          const float* __restrict__ biasc, uint32_t* __restrict__ flags,
          int t0, int nsteps) {
    __shared__ ushort Wl[32 * 1536];      // 96 KB
    __shared__ ushort hout[64][8];        // 1 KB
    const int g = blockIdx.x, tid = threadIdx.x;
    const int lane = tid & 63, w = tid >> 6;
    const int n0 = g * 32;
    const int l15 = lane & 15, lq = lane >> 4;

    // stage W slice (swizzled): 32 rows x 192 16B chunks
    {
        char* p = (char*)Wl;
        for (int i = tid; i < 32 * 192; i += 256) {
            const int row = i / 192, c8 = i - row * 192;
            bs8 v = *reinterpret_cast<const bs8*>(WcT + (size_t)(n0 + row) * KC + c8 * 8);
            *reinterpret_cast<bs8*>(p + WSWZ(row, c8 * 16)) = v;
        }
    }
    const char* wl = (const char*)Wl;

    const int bmy = w * 16 + l15;          // my b
    const int u0 = g * 8;                  // first h-unit of this WG
    const f4 bia0 = *reinterpret_cast<const f4*>(biasc + n0 + lq * 4);
    const f4 bia1 = *reinterpret_cast<const f4*>(biasc + n0 + 16 + lq * 4);
    float c0 = 0.f, c1 = 0.f;
    if (t0 != 0) {
        c0 = cst[(size_t)bmy * H_ + u0 + lq];
        c1 = cst[(size_t)bmy * H_ + u0 + 4 + lq];
    }
    const ushort* xbase = xP + (size_t)t0 * 32768 + (size_t)bmy * 32 + lq * 8;
    const ushort* hrd   = hs + (size_t)bmy * 32 + lq * 8;
    __syncthreads();

    bs8 xv[16];
#pragma unroll
    for (int kk = 0; kk < 16; ++kk)
        xv[kk] = *reinterpret_cast<const bs8*>(xbase + kk * 2048);

    for (int s = 0; s < nsteps; ++s) {
        // h_s visibility gated by previous iteration's poll (s=0: launch boundary)
        const ushort* hb = hrd + (size_t)s * BH;
        bs8 hv0[16], hv1[16];
#pragma unroll
        for (int kk = 0; kk < 16; ++kk)
            hv0[kk] = *reinterpret_cast<const bs8*>(hb + kk * 2048);

        f4 a0 = {0.f, 0.f, 0.f, 0.f}, a1 = {0.f, 0.f, 0.f, 0.f};
#pragma unroll
        for (int kk = 0; kk < 16; ++kk) {
            bs8 wa0 = *reinterpret_cast<const bs8*>(wl + WSWZ(l15,      kk * 64 + lq * 16));
            bs8 wa1 = *reinterpret_cast<const bs8*>(wl + WSWZ(16 + l15, kk * 64 + lq * 16));
            a0 = __builtin_amdgcn_mfma_f32_16x16x32_bf16(wa0, xv[kk], a0, 0, 0, 0);
            a1 = __builtin_amdgcn_mfma_f32_16x16x32_bf16(wa1, xv[kk], a1, 0, 0, 0);
        }
#pragma unroll
        for (int kk = 0; kk < 16; ++kk)
            hv1[kk] = *reinterpret_cast<const bs8*>(hb + (16 + kk) * 2048);
#pragma unroll
        for (int kk = 0; kk < 16; ++kk) {
            bs8 wa0 = *reinterpret_cast<const bs8*>(wl + WSWZ(l15,      1024 + kk * 64 + lq * 16));
            bs8 wa1 = *reinterpret_cast<const bs8*>(wl + WSWZ(16 + l15, 1024 + kk * 64 + lq * 16));
            a0 = __builtin_amdgcn_mfma_f32_16x16x32_bf16(wa0, hv0[kk], a0, 0, 0, 0);
            a1 = __builtin_amdgcn_mfma_f32_16x16x32_bf16(wa1, hv0[kk], a1, 0, 0, 0);
        }
#pragma unroll
        for (int kk = 0; kk < 16; ++kk) {
            bs8 wa0 = *reinterpret_cast<const bs8*>(wl + WSWZ(l15,      2048 + kk * 64 + lq * 16));
            bs8 wa1 = *reinterpret_cast<const bs8*>(wl + WSWZ(16 + l15, 2048 + kk * 64 + lq * 16));
            a0 = __builtin_amdgcn_mfma_f32_16x16x32_bf16(wa0, hv1[kk], a0, 0, 0, 0);
            a1 = __builtin_amdgcn_mfma_f32_16x16x32_bf16(wa1, hv1[kk], a1, 0, 0, 0);
        }

        // elementwise: cells (b=bmy, u0+lq) and (b=bmy, u0+4+lq)
        {
            float pi = a0[0] + bia0[0], pf = a0[1] + bia0[1];
            float po = a0[2] + bia0[2], pc = a0[3] + bia0[3];
            float iv = sigm(pi), fv = sigm(pf), ov = sigm(po), cv = tanh_(pc);
            c0 = fv * c0 + iv * cv;
            hout[bmy][lq] = f2bf(ov * tanh_(c0));
        }
        {
            float pi = a1[0] + bia1[0], pf = a1[1] + bia1[1];
            float po = a1[2] + bia1[2], pc = a1[3] + bia1[3];
            float iv = sigm(pi), fv = sigm(pf), ov = sigm(po), cv = tanh_(pc);
            c1 = fv * c1 + iv * cv;
            hout[bmy][4 + lq] = f2bf(ov * tanh_(c1));
        }
        __syncthreads();   // all waves' hout rows complete before wave0 reads

        if (w == 0) {
            f4 hv = *reinterpret_cast<f4*>(&hout[lane][0]);
            ushort* dst = hs + (size_t)(s + 1) * BH + (size_t)(g >> 2) * 2048
                        + (size_t)lane * 32 + (g & 3) * 8;
            coh_store16(dst, hv);
            asm volatile("s_waitcnt vmcnt(0)" ::: "memory");
            if (tid == 0)
                __hip_atomic_store(&flags[g], (uint32_t)(s + 1),
                                   __ATOMIC_RELAXED, __HIP_MEMORY_SCOPE_AGENT);
        }

        if (s + 1 < nsteps) {
            // issue next-step x loads before waiting
#pragma unroll
            for (int kk = 0; kk < 16; ++kk)
                xv[kk] = *reinterpret_cast<const bs8*>(xbase + (size_t)(s + 1) * 32768 + kk * 2048);
            if (w == 0) {
                const uint32_t tgt = (uint32_t)(s + 1);
                for (;;) {
                    uint32_t f0 = __hip_atomic_load(&flags[lane], __ATOMIC_RELAXED,
                                                    __HIP_MEMORY_SCOPE_AGENT);
                    uint32_t f1 = __hip_atomic_load(&flags[64 + lane], __ATOMIC_RELAXED,
                                                    __HIP_MEMORY_SCOPE_AGENT);
                    if (__all((int)(f0 >= tgt && f1 >= tgt))) break;
                    __builtin_amdgcn_s_sleep(1);
                }
            }
            __syncthreads();   // release all waves; h_{s+1} visible
        }
    }

    cst[(size_t)bmy * H_ + u0 + lq]     = c0;
    cst[(size_t)bmy * H_ + u0 + 4 + lq] = c1;
}

// ---------------- output projection (packed h input) ----------------
// block (tloc, o-tile): y[b][t][o] for one t, all 64 b, 64 o.
__global__ void __launch_bounds__(64) k_yproj(const ushort* __restrict__ WhyT,
                                              const ushort* __restrict__ hsbase,
                                              const float* __restrict__ by,
                                              float* __restrict__ out, int t_off) {
    const int lane = threadIdx.x;
    const int tloc = blockIdx.x;
    const int o0 = blockIdx.y * 64;
    const int l15 = lane & 15, lq = lane >> 4, lk = lq * 8;
    const int t = t_off + tloc;

    const ushort* slot = hsbase + (size_t)(tloc + 1) * BH;
    const ushort* apm[4]; const ushort* bp[4];
#pragma unroll
    for (int m = 0; m < 4; ++m) apm[m] = WhyT + (size_t)(o0 + m * 16 + l15) * H_ + lk;
#pragma unroll
    for (int n = 0; n < 4; ++n) bp[n] = slot + (size_t)(n * 16 + l15) * 32 + lk;

    f4 acc[4][4] = {};
    for (int kk = 0; kk < 32; ++kk) {
        bs8 a[4], b[4];
#pragma unroll
        for (int m = 0; m < 4; ++m) a[m] = *reinterpret_cast<const bs8*>(apm[m] + kk * 32);
#pragma unroll
        for (int n = 0; n < 4; ++n) b[n] = *reinterpret_cast<const bs8*>(bp[n] + (size_t)kk * 2048);
#pragma unroll
        for (int m = 0; m < 4; ++m)
#pragma unroll
            for (int n = 0; n < 4; ++n)
                acc[m][n] = __builtin_amdgcn_mfma_f32_16x16x32_bf16(a[m], b[n], acc[m][n], 0, 0, 0);
    }

#pragma unroll
    for (int m = 0; m < 4; ++m) {
        const int ob = o0 + m * 16 + lq * 4;
        const f4 bb = *reinterpret_cast<const f4*>(by + ob);
#pragma unroll
        for (int n = 0; n < 4; ++n) {
            const int b_ = n * 16 + l15;
            f4 v = acc[m][n] + bb;
            *reinterpret_cast<f4*>(out + ((size_t)b_ * T_ + t) * O_ + ob) = v;
        }
    }
}

// ---------------- launch ----------------

extern "C" void kernel_launch(void* const* d_in, const int* in_sizes, int n_in,
                              void* d_out, int out_size, void* d_ws, size_t ws_size,
                              hipStream_t stream) {
    const float* x   = (const float*)d_in[0];
    const float* wxi = (const float*)d_in[1];
    const float* whi = (const float*)d_in[2];
    const float* bi  = (const float*)d_in[3];
    const float* wxf = (const float*)d_in[4];
    const float* whf = (const float*)d_in[5];
    const float* bf_ = (const float*)d_in[6];
    const float* wxo = (const float*)d_in[7];
    const float* who = (const float*)d_in[8];
    const float* bo  = (const float*)d_in[9];
    const float* wxc = (const float*)d_in[10];
    const float* whc = (const float*)d_in[11];
    const float* bc  = (const float*)d_in[12];
    const float* why = (const float*)d_in[13];
    const float* by  = (const float*)d_in[14];
    float* out = (float*)d_out;

    uint8_t* w = (uint8_t*)d_ws;
    ushort*   xP    = (ushort*)  (w);                  // 33,554,432
    ushort*   WcT   = (ushort*)  (w + 33554432);       // 12,582,912
    ushort*   WhyT  = (ushort*)  (w + 46137344);       //  1,048,576
    float*    biasc = (float*)   (w + 47185920);       //     16,384
    float*    cst   = (float*)   (w + 47202304);       //    262,144
    uint32_t* flags = (uint32_t*)(w + 47464448);       //      4,096
    ushort*   hs    = (ushort*)  (w + 47468544);
    const size_t NEED_A = 47468544 + (size_t)(T_ + 1) * BH * 2;  // 114,708,480
    const size_t NEED_B = 47468544 + (size_t)65 * BH * 2;        //  55,988,224
    if (ws_size < NEED_B) return;
    const bool fullhs = (ws_size >= NEED_A);

    k_pack_x<<<2048, 256, 0, stream>>>(x, xP);
    k_build_wcT<<<4096, 256, 0, stream>>>(wxi, wxf, wxo, wxc, whi, whf, who, whc, WcT);
    k_build_whyT<<<512, 256, 0, stream>>>(why, WhyT);
    k_build_bias<<<16, 256, 0, stream>>>(bi, bf_, bo, bc, biasc);

    hipMemsetAsync(cst, 0, (size_t)BH * 4, stream);
    hipMemsetAsync(hs,  0, (size_t)BH * 2, stream);

    const int nchunk = fullhs ? 1 : 8;
    const int steps  = fullhs ? T_ : 64;
    for (int c = 0; c < nchunk; ++c) {
        const int t0 = c * steps;
        hipMemsetAsync(flags, 0, NWG * 4, stream);
        const ushort* a0 = WcT; const ushort* a1 = xP; ushort* a2 = hs;
        float* a3 = cst; const float* a4 = biasc; uint32_t* a5 = flags;
        int a6 = t0, a7 = steps;
        void* args[8] = {&a0, &a1, &a2, &a3, &a4, &a5, &a6, &a7};
        hipError_t e = hipLaunchCooperativeKernel((const void*)k_persist,
                                                  dim3(NWG), dim3(256), args, 0, stream);
        if (e != hipSuccess) {
            // co-residency fallback: 128 blocks with 97KB LDS -> 1 WG/CU, all resident
            k_persist<<<dim3(NWG), dim3(256), 0, stream>>>(WcT, xP, hs, cst, biasc,
                                                           flags, t0, steps);
        }
        if (!fullhs) {
            k_yproj<<<dim3(64, O_ / 64), 64, 0, stream>>>(WhyT, hs, by, out, t0);
            if (c != nchunk - 1)
                hipMemcpyAsync(hs, hs + (size_t)64 * BH, (size_t)BH * 2,
                               hipMemcpyDeviceToDevice, stream);
        }
    }
    if (fullhs)
        k_yproj<<<dim3(T_, O_ / 64), 64, 0, stream>>>(WhyT, hs, by, out, 0);
}